// Round 1
// baseline (500.497 us; speedup 1.0000x reference)
//
#include <hip/hip_runtime.h>

#define NN 96
#define N3 (96*96*96)

__device__ __forceinline__ int wm(int i){ return i==0    ? NN-1 : i-1; }
__device__ __forceinline__ int wp(int i){ return i==NN-1 ? 0    : i+1; }

struct Idx { int p, xm, xp, ym, yp, zm, zp; };

__device__ __forceinline__ Idx make_idx(){
  int z = threadIdx.x;
  int y = blockIdx.x * blockDim.y + threadIdx.y;
  int x = blockIdx.y;
  Idx I;
  I.p  = (x*NN+y)*NN+z;
  I.xm = (wm(x)*NN+y)*NN+z;
  I.xp = (wp(x)*NN+y)*NN+z;
  I.ym = (x*NN+wm(y))*NN+z;
  I.yp = (x*NN+wp(y))*NN+z;
  I.zm = (x*NN+y)*NN+wm(z);
  I.zp = (x*NN+y)*NN+wp(z);
  return I;
}

// AoS [p][3] -> SoA [c][p]
__global__ void k_convert(const float* __restrict__ in, float* __restrict__ v){
  int i = blockIdx.x*256 + threadIdx.x;
  if (i < N3){
    v[i]        = in[3*i];
    v[N3+i]     = in[3*i+1];
    v[2*N3+i]   = in[3*i+2];
  }
}

// step 0: dis = -dt*v  (w = jac(0, v) = 0)
__global__ void k_dis0(const float* __restrict__ v, float* __restrict__ d){
  int i = blockIdx.x*256 + threadIdx.x;
  if (i < 3*N3) d[i] = -0.1f * v[i];
}

// dis_new_i = dis_i - dt*( sum_j d_j(dis_i)*v_j + v_i )
__global__ __launch_bounds__(384) void k_dis(const float* __restrict__ dis,
    const float* __restrict__ v, float* __restrict__ dout,
    float* __restrict__ out_ilv, int last)
{
  Idx I = make_idx();
  float vv[3] = { v[I.p], v[N3+I.p], v[2*N3+I.p] };
  #pragma unroll
  for (int c=0;c<3;c++){
    const float* d = dis + c*N3;
    float gx = 0.5f*(d[I.xp]-d[I.xm]);
    float gy = 0.5f*(d[I.yp]-d[I.ym]);
    float gz = 0.5f*(d[I.zp]-d[I.zm]);
    float w  = gx*vv[0] + gy*vv[1] + gz*vv[2];
    float r  = d[I.p] - 0.1f*(w + vv[c]);
    if (last) out_ilv[I.p*3+c] = r;
    else      dout[c*N3+I.p]   = r;
  }
}

// m = L v = v + eps*(6v - sum of 6 neighbors)
__global__ __launch_bounds__(384) void k_m(const float* __restrict__ v, float* __restrict__ m){
  Idx I = make_idx();
  #pragma unroll
  for (int c=0;c<3;c++){
    const float* s = v + c*N3;
    float c0 = s[I.p];
    m[c*N3+I.p] = c0 + 0.0025f*(6.0f*c0 - s[I.xm]-s[I.xp]-s[I.ym]-s[I.yp]-s[I.zm]-s[I.zp]);
  }
}

// t_i = sum_c d_i(v_c)*m_c + sum_j d_j(m_i * v_j)
__global__ __launch_bounds__(384) void k_t(const float* __restrict__ v,
    const float* __restrict__ m, float* __restrict__ t)
{
  Idx I = make_idx();
  int nbm[3] = {I.xm, I.ym, I.zm};
  int nbp[3] = {I.xp, I.yp, I.zp};
  float mc[3], vn_m[3][3], vn_p[3][3], mn_m[3][3], mn_p[3][3];
  #pragma unroll
  for (int c=0;c<3;c++) mc[c] = m[c*N3+I.p];
  #pragma unroll
  for (int a=0;a<3;a++){
    #pragma unroll
    for (int c=0;c<3;c++){
      vn_m[a][c] = v[c*N3+nbm[a]];
      vn_p[a][c] = v[c*N3+nbp[a]];
      mn_m[a][c] = m[c*N3+nbm[a]];
      mn_p[a][c] = m[c*N3+nbp[a]];
    }
  }
  #pragma unroll
  for (int i=0;i<3;i++){
    float t1 = 0.f, t2 = 0.f;
    #pragma unroll
    for (int c=0;c<3;c++)
      t1 += 0.5f*(vn_p[i][c]-vn_m[i][c]) * mc[c];
    #pragma unroll
    for (int j=0;j<3;j++)
      t2 += 0.5f*( mn_p[j][i]*vn_p[j][j] - mn_m[j][i]*vn_m[j][j] );
    t[i*N3+I.p] = t1 + t2;
  }
}

// u_next = t - eps*(6u - sum of neighbors of u)   (Neumann iteration for K = L^-1)
__global__ __launch_bounds__(384) void k_iter(const float* __restrict__ t,
    const float* __restrict__ u, float* __restrict__ un)
{
  Idx I = make_idx();
  #pragma unroll
  for (int c=0;c<3;c++){
    const float* s = u + c*N3;
    float uc = s[I.p];
    un[c*N3+I.p] = t[c*N3+I.p] - 0.0025f*(6.0f*uc - s[I.xm]-s[I.xp]-s[I.ym]-s[I.yp]-s[I.zm]-s[I.zp]);
  }
}

// final iteration fused with v update: v -= dt * (t - eps*A u)
__global__ __launch_bounds__(384) void k_vup(const float* __restrict__ t,
    const float* __restrict__ u, float* __restrict__ v)
{
  Idx I = make_idx();
  #pragma unroll
  for (int c=0;c<3;c++){
    const float* s = u + c*N3;
    float uc = s[I.p];
    float un = t[c*N3+I.p] - 0.0025f*(6.0f*uc - s[I.xm]-s[I.xp]-s[I.ym]-s[I.yp]-s[I.zm]-s[I.zp]);
    v[c*N3+I.p] -= 0.1f*un;
  }
}

extern "C" void kernel_launch(void* const* d_in, const int* in_sizes, int n_in,
                              void* d_out, int out_size, void* d_ws, size_t ws_size,
                              hipStream_t stream)
{
  const float* v0 = (const float*)d_in[0];
  float* out = (float*)d_out;
  float* ws  = (float*)d_ws;

  float* v    = ws;             // 3*N3
  float* disA = v    + 3*N3;    // 3*N3
  float* disB = disA + 3*N3;    // 3*N3
  float* mbuf = disB + 3*N3;    // 3*N3 (also Neumann ping buffer)
  float* tbuf = mbuf + 3*N3;    // 3*N3

  dim3 blk(96,4,1), grd(24,96,1);

  k_convert<<<(N3+255)/256, 256, 0, stream>>>(v0, v);

  float* dcur  = disA;
  float* dfree = disB;   // free dis buffer doubles as Neumann pong buffer

  for (int s=0; s<10; s++){
    if (s == 0){
      k_dis0<<<(3*N3+255)/256, 256, 0, stream>>>(v, dcur);
    } else {
      int last = (s==9) ? 1 : 0;
      k_dis<<<grd, blk, 0, stream>>>(dcur, v, dfree, out, last);
      if (last) break;
      float* tmp = dcur; dcur = dfree; dfree = tmp;
    }
    // v <- v - dt * K( t1 + t2 )
    k_m   <<<grd, blk, 0, stream>>>(v, mbuf);
    k_t   <<<grd, blk, 0, stream>>>(v, mbuf, tbuf);
    k_iter<<<grd, blk, 0, stream>>>(tbuf, tbuf, dfree);  // u1 (u0 = t)
    k_iter<<<grd, blk, 0, stream>>>(tbuf, dfree, mbuf);  // u2
    k_iter<<<grd, blk, 0, stream>>>(tbuf, mbuf, dfree);  // u3
    k_iter<<<grd, blk, 0, stream>>>(tbuf, dfree, mbuf);  // u4
    k_vup <<<grd, blk, 0, stream>>>(tbuf, mbuf, v);      // u5 + v update
  }
}

// Round 2
// 247.355 us; speedup vs baseline: 2.0234x; 2.0234x over previous
//
#include <hip/hip_runtime.h>

#define NN 96
#define N3 (96*96*96)
#define EPS 0.0025f
#define DT  0.1f

__device__ __forceinline__ int wm(int i){ return i==0    ? NN-1 : i-1; }
__device__ __forceinline__ int wp(int i){ return i==NN-1 ? 0    : i+1; }
__device__ __forceinline__ int IDX(int x,int y,int z){ return (x*NN+y)*NN+z; }

// m = (L v) at one point, given wrapped coord triplets per axis
__device__ __forceinline__ float Lop(const float* __restrict__ s,
    int xm,int x,int xp, int ym,int y,int yp, int zm,int z,int zp){
  float c = s[IDX(x,y,z)];
  float sum = s[IDX(xm,y,z)] + s[IDX(xp,y,z)]
            + s[IDX(x,ym,z)] + s[IDX(x,yp,z)]
            + s[IDX(x,y,zm)] + s[IDX(x,y,zp)];
  return fmaf(EPS, 6.0f*c - sum, c);
}

// AoS [p][3] -> SoA [c][p]
__global__ void k_convert(const float* __restrict__ in, float* __restrict__ v){
  int i = blockIdx.x*256 + threadIdx.x;
  if (i < N3){
    v[i]      = in[3*i];
    v[N3+i]   = in[3*i+1];
    v[2*N3+i] = in[3*i+2];
  }
}

// Kernel A: dis_new = dis - dt*(grad(dis)·v + v), and t = t1+t2 (m recomputed on the fly).
// ZERO_DIS: dis input is identically zero (step 0). LAST: write dis interleaved to out, skip t.
template<int ZERO_DIS, int LAST>
__global__ __launch_bounds__(384) void k_A(const float* __restrict__ dis,
    const float* __restrict__ v, float* __restrict__ dout,
    float* __restrict__ t, float* __restrict__ out_ilv)
{
  int z = threadIdx.x;
  int y = blockIdx.x*4 + threadIdx.y;
  int x = blockIdx.y;
  int xm=wm(x), xp=wp(x), xm2=wm(xm), xp2=wp(xp);
  int ym=wm(y), yp=wp(y), ym2=wm(ym), yp2=wp(yp);
  int zm=wm(z), zp=wp(z), zm2=wm(zm), zp2=wp(zp);
  int p = IDX(x,y,z);

  float vv[3] = { v[p], v[N3+p], v[2*N3+p] };

  // ---- dis update ----
  #pragma unroll
  for (int c=0;c<3;c++){
    float r;
    if (ZERO_DIS){
      r = -DT * vv[c];
    } else {
      const float* d = dis + c*N3;
      float gx = 0.5f*(d[IDX(xp,y,z)] - d[IDX(xm,y,z)]);
      float gy = 0.5f*(d[IDX(x,yp,z)] - d[IDX(x,ym,z)]);
      float gz = 0.5f*(d[IDX(x,y,zp)] - d[IDX(x,y,zm)]);
      float w  = gx*vv[0] + gy*vv[1] + gz*vv[2];
      r = d[p] - DT*(w + vv[c]);
    }
    if (LAST) out_ilv[p*3+c] = r;
    else      dout[c*N3+p]   = r;
  }
  if (LAST) return;

  // ---- t = t1 + t2 with m computed on the fly ----
  float mc[3], mxm[3], mxp[3], mym[3], myp[3], mzm[3], mzp[3];
  float vxm[3], vxp[3], vym[3], vyp[3], vzm[3], vzp[3];
  #pragma unroll
  for (int c=0;c<3;c++){
    const float* s = v + c*N3;
    mc [c] = Lop(s, xm,x,xp,   ym,y,yp,   zm,z,zp);
    mxm[c] = Lop(s, xm2,xm,x,  ym,y,yp,   zm,z,zp);
    mxp[c] = Lop(s, x,xp,xp2,  ym,y,yp,   zm,z,zp);
    mym[c] = Lop(s, xm,x,xp,   ym2,ym,y,  zm,z,zp);
    myp[c] = Lop(s, xm,x,xp,   y,yp,yp2,  zm,z,zp);
    mzm[c] = Lop(s, xm,x,xp,   ym,y,yp,   zm2,zm,z);
    mzp[c] = Lop(s, xm,x,xp,   ym,y,yp,   z,zp,zp2);
    vxm[c] = s[IDX(xm,y,z)];  vxp[c] = s[IDX(xp,y,z)];
    vym[c] = s[IDX(x,ym,z)];  vyp[c] = s[IDX(x,yp,z)];
    vzm[c] = s[IDX(x,y,zm)];  vzp[c] = s[IDX(x,y,zp)];
  }
  #pragma unroll
  for (int i=0;i<3;i++){
    // t1_i = sum_c d_i(v_c) * m_c(p)
    float g0, g1, g2;
    if (i==0){ g0 = vxp[0]-vxm[0]; g1 = vxp[1]-vxm[1]; g2 = vxp[2]-vxm[2]; }
    else if (i==1){ g0 = vyp[0]-vym[0]; g1 = vyp[1]-vym[1]; g2 = vyp[2]-vym[2]; }
    else { g0 = vzp[0]-vzm[0]; g1 = vzp[1]-vzm[1]; g2 = vzp[2]-vzm[2]; }
    float t1 = 0.5f*(g0*mc[0] + g1*mc[1] + g2*mc[2]);
    // t2_i = sum_j d_j(m_i * v_j)
    float t2 = 0.5f*( mxp[i]*vxp[0] - mxm[i]*vxm[0]
                    + myp[i]*vyp[1] - mym[i]*vym[1]
                    + mzp[i]*vzp[2] - mzm[i]*vzm[2] );
    t[i*N3+p] = t1 + t2;
  }
}

// Kernel C: v -= dt * (I - eps*A) t   (single Neumann term for K = L^-1)
__global__ __launch_bounds__(384) void k_C(const float* __restrict__ t, float* __restrict__ v)
{
  int z = threadIdx.x;
  int y = blockIdx.x*4 + threadIdx.y;
  int x = blockIdx.y;
  int xm=wm(x), xp=wp(x);
  int ym=wm(y), yp=wp(y);
  int zm=wm(z), zp=wp(z);
  int p = IDX(x,y,z);
  #pragma unroll
  for (int c=0;c<3;c++){
    const float* s = t + c*N3;
    float tc = s[p];
    float sum = s[IDX(xm,y,z)] + s[IDX(xp,y,z)]
              + s[IDX(x,ym,z)] + s[IDX(x,yp,z)]
              + s[IDX(x,y,zm)] + s[IDX(x,y,zp)];
    float u = tc - EPS*(6.0f*tc - sum);
    v[c*N3+p] -= DT*u;
  }
}

extern "C" void kernel_launch(void* const* d_in, const int* in_sizes, int n_in,
                              void* d_out, int out_size, void* d_ws, size_t ws_size,
                              hipStream_t stream)
{
  const float* v0 = (const float*)d_in[0];
  float* out = (float*)d_out;
  float* ws  = (float*)d_ws;

  float* v    = ws;            // 3*N3
  float* disA = v    + 3*N3;   // 3*N3
  float* disB = disA + 3*N3;   // 3*N3
  float* tbuf = disB + 3*N3;   // 3*N3

  dim3 blk(96,4,1), grd(24,96,1);

  k_convert<<<(N3+255)/256, 256, 0, stream>>>(v0, v);

  float* dcur  = disA;
  float* dfree = disB;

  for (int s=0; s<10; s++){
    if (s == 0){
      k_A<1,0><<<grd, blk, 0, stream>>>(nullptr, v, dcur, tbuf, nullptr);
    } else if (s == 9){
      k_A<0,1><<<grd, blk, 0, stream>>>(dcur, v, nullptr, nullptr, out);
      break;
    } else {
      k_A<0,0><<<grd, blk, 0, stream>>>(dcur, v, dfree, tbuf, nullptr);
      float* tmp = dcur; dcur = dfree; dfree = tmp;
    }
    k_C<<<grd, blk, 0, stream>>>(tbuf, v);
  }
}